// Round 2
// baseline (27063.055 us; speedup 1.0000x reference)
//
#include <hip/hip_runtime.h>

#define HDIM 256
#define EPSV 1e-5f
#define SLOPEV 0.01f

// ---------------- GEMM: C[n x m] = (ADD?C:0) + A[n x k] * W[k x m](ld ldw) + (BIAS?bias:0)
template<bool ADD, bool BIAS>
__global__ __launch_bounds__(256)
void gemm_k(const float* __restrict__ A, const float* __restrict__ W,
            const float* __restrict__ bias, float* __restrict__ C,
            int n, int k, int m, int ldw)
{
    __shared__ float As[16][68];
    __shared__ float Ws[16][68];
    const int tid = threadIdx.x;
    const int bm = blockIdx.y * 64;   // row base
    const int bn = blockIdx.x * 64;   // col base
    const int ty = tid >> 4, tx = tid & 15;
    float acc[4][4] = {};

    for (int kt = 0; kt < k; kt += 16) {
        // A tile 64 rows x 16 k  (thread: row tid>>2, 4 consecutive k)
        {
            int r  = tid >> 2;
            int kk = (tid & 3) * 4;
            int row = bm + r;
            float4 v = make_float4(0.f, 0.f, 0.f, 0.f);
            if (row < n) v = *(const float4*)(A + (size_t)row * k + kt + kk);
            As[kk + 0][r] = v.x; As[kk + 1][r] = v.y;
            As[kk + 2][r] = v.z; As[kk + 3][r] = v.w;
        }
        // W tile 16 k x 64 cols (thread: kk tid>>4, 4 consecutive cols)
        {
            int kk = tid >> 4;
            int c  = (tid & 15) * 4;
            float4 v = *(const float4*)(W + (size_t)(kt + kk) * ldw + bn + c);
            *(float4*)(&Ws[kk][c]) = v;   // stride 68 floats = 272B, 16B aligned
        }
        __syncthreads();
#pragma unroll
        for (int kk = 0; kk < 16; ++kk) {
            float a0 = As[kk][ty * 4 + 0], a1 = As[kk][ty * 4 + 1];
            float a2 = As[kk][ty * 4 + 2], a3 = As[kk][ty * 4 + 3];
            float w0 = Ws[kk][tx * 4 + 0], w1 = Ws[kk][tx * 4 + 1];
            float w2 = Ws[kk][tx * 4 + 2], w3 = Ws[kk][tx * 4 + 3];
            acc[0][0] += a0 * w0; acc[0][1] += a0 * w1; acc[0][2] += a0 * w2; acc[0][3] += a0 * w3;
            acc[1][0] += a1 * w0; acc[1][1] += a1 * w1; acc[1][2] += a1 * w2; acc[1][3] += a1 * w3;
            acc[2][0] += a2 * w0; acc[2][1] += a2 * w1; acc[2][2] += a2 * w2; acc[2][3] += a2 * w3;
            acc[3][0] += a3 * w0; acc[3][1] += a3 * w1; acc[3][2] += a3 * w2; acc[3][3] += a3 * w3;
        }
        __syncthreads();
    }

    float4 bv = make_float4(0.f, 0.f, 0.f, 0.f);
    if (BIAS) bv = *(const float4*)(bias + bn + tx * 4);
#pragma unroll
    for (int i = 0; i < 4; ++i) {
        int row = bm + ty * 4 + i;
        if (row >= n) break;
        float* cp = C + (size_t)row * m + bn + tx * 4;
        float4 r = make_float4(acc[i][0], acc[i][1], acc[i][2], acc[i][3]);
        if (BIAS) { r.x += bv.x; r.y += bv.y; r.z += bv.z; r.w += bv.w; }
        if (ADD) {
            float4 o = *(const float4*)cp;
            r.x += o.x; r.y += o.y; r.z += o.z; r.w += o.w;
        }
        *(float4*)cp = r;
    }
}

// ---------------- scatter: Q[dst[e]] += w[e] * P[src[e]]   (one wave per edge, H=256)
__global__ __launch_bounds__(256)
void spmm_scatter_k(const float* __restrict__ P, const int* __restrict__ src,
                    const int* __restrict__ dst, const float* __restrict__ ew,
                    float* __restrict__ Q, int E)
{
    int gid  = blockIdx.x * blockDim.x + threadIdx.x;
    int e    = gid >> 6;
    int lane = threadIdx.x & 63;
    if (e >= E) return;
    int s = src[e];
    int d = dst[e];
    float w = ew[e];
    float4 v = *(const float4*)(P + (size_t)s * HDIM + lane * 4);
    float* qp = Q + (size_t)d * HDIM + lane * 4;
    unsafeAtomicAdd(qp + 0, v.x * w);
    unsafeAtomicAdd(qp + 1, v.y * w);
    unsafeAtomicAdd(qp + 2, v.z * w);
    unsafeAtomicAdd(qp + 3, v.w * w);
}

// ---------------- column stats: sums[c] += sum_r X[r][c]; sums[256+c] += sum_r X^2
__global__ __launch_bounds__(256)
void colstats_k(const float* __restrict__ X, float* __restrict__ sums, int n)
{
    int c = threadIdx.x;           // 256 cols
    float s = 0.f, s2 = 0.f;
    for (int r = blockIdx.x; r < n; r += gridDim.x) {
        float v = X[(size_t)r * HDIM + c];
        s += v; s2 += v * v;
    }
    unsafeAtomicAdd(&sums[c], s);
    unsafeAtomicAdd(&sums[HDIM + c], s2);
}

// ---------------- finalize BN affine: a = g*rsqrt(var+eps); b' = b - mean*a
__global__ __launch_bounds__(256)
void finalize_k(const float* __restrict__ sums, const float* __restrict__ g,
                const float* __restrict__ b, float* __restrict__ ab, float invn)
{
    int c = threadIdx.x;
    float mean = sums[c] * invn;
    float var  = sums[HDIM + c] * invn - mean * mean;
    float a = g[c] * rsqrtf(var + EPSV);
    ab[c]        = a;
    ab[HDIM + c] = b[c] - mean * a;
}

// ---------------- y = leaky_relu(a*x + b') elementwise over N x 256
__global__ __launch_bounds__(256)
void apply_bn_leaky_k(const float* __restrict__ X, const float* __restrict__ ab,
                      float* __restrict__ Y, long n4)
{
    long i0 = (long)blockIdx.x * blockDim.x + threadIdx.x;
    long stride = (long)gridDim.x * blockDim.x;
    for (long i = i0; i < n4; i += stride) {
        float4 v = ((const float4*)X)[i];
        int c4 = (int)(i & 63);
        float4 a = ((const float4*)ab)[c4];
        float4 b = ((const float4*)(ab + HDIM))[c4];
        float4 r;
        r.x = fmaf(v.x, a.x, b.x); r.x = r.x > 0.f ? r.x : SLOPEV * r.x;
        r.y = fmaf(v.y, a.y, b.y); r.y = r.y > 0.f ? r.y : SLOPEV * r.y;
        r.z = fmaf(v.z, a.z, b.z); r.z = r.z > 0.f ? r.z : SLOPEV * r.z;
        r.w = fmaf(v.w, a.w, b.w); r.w = r.w > 0.f ? r.w : SLOPEV * r.w;
        ((float4*)Y)[i] = r;
    }
}

// ================= host orchestration =================
static void gemm(hipStream_t st, const float* A, const float* W, const float* bias,
                 float* C, int n, int k, int m, int ldw, bool add, bool biasb)
{
    dim3 g(m / 64, (n + 63) / 64), b(256);
    if (add) {
        if (biasb) gemm_k<true, true><<<g, b, 0, st>>>(A, W, bias, C, n, k, m, ldw);
        else       gemm_k<true, false><<<g, b, 0, st>>>(A, W, bias, C, n, k, m, ldw);
    } else {
        if (biasb) gemm_k<false, true><<<g, b, 0, st>>>(A, W, bias, C, n, k, m, ldw);
        else       gemm_k<false, false><<<g, b, 0, st>>>(A, W, bias, C, n, k, m, ldw);
    }
}

extern "C" void kernel_launch(void* const* d_in, const int* in_sizes, int n_in,
                              void* d_out, int out_size, void* d_ws, size_t ws_size,
                              hipStream_t stream)
{
    const float* x       = (const float*)d_in[0];
    const int*   ei      = (const int*)d_in[1];     // int64 in reference -> int32 from harness
    const float* ew      = (const float*)d_in[2];
    const float* W_emb   = (const float*)d_in[3];
    const float* b_emb   = (const float*)d_in[4];
    const float* conv0_W = (const float*)d_in[5];
    const float* conv0_b = (const float*)d_in[6];
    const float* norm_g  = (const float*)d_in[7];
    const float* norm_b  = (const float*)d_in[8];
    const float* conv_W  = (const float*)d_in[9];
    const float* conv_b  = (const float*)d_in[10];
    const float* mlp_W1  = (const float*)d_in[11];
    const float* mlp_b1  = (const float*)d_in[12];
    const float* mlp_g   = (const float*)d_in[13];
    const float* mlp_bb  = (const float*)d_in[14];
    const float* mlp_W2  = (const float*)d_in[15];
    const float* mlp_b2  = (const float*)d_in[16];
    const float* W_out   = (const float*)d_in[17];
    const float* b_out   = (const float*)d_in[18];

    const int N = in_sizes[0] / 128;          // 50000
    const int E = in_sizes[2];                // 800000
    const int* srcI = ei;
    const int* dstI = ei + E;

    const size_t NH = (size_t)N * HDIM;
    float* A_ = (float*)d_ws;
    float* B_ = A_ + NH;
    float* Cb = B_ + NH;
    float* Db = Cb + NH;
    float* stats = Db + NH;      // 512 floats
    float* ab    = stats + 512;  // 512 floats

    const size_t HH = (size_t)HDIM * HDIM;    // 65536
    dim3 sg((E + 3) / 4), sb(256);
    const long n4 = (long)NH / 4;
    dim3 ag(12544), abk(256);
    const float invn = 1.0f / (float)N;

    // h = x @ W_emb + b_emb -> A_
    gemm(stream, x, W_emb, b_emb, A_, N, 128, HDIM, HDIM, false, true);

    // conv0: B_ = A_@W0 + b ; + (A.A_)@W1 ; + (A^2.A_)@W2
    gemm(stream, A_, conv0_W, conv0_b, B_, N, HDIM, HDIM, HDIM, false, true);
    hipMemsetAsync(Cb, 0, NH * 4, stream);
    spmm_scatter_k<<<sg, sb, 0, stream>>>(A_, srcI, dstI, ew, Cb, E);
    gemm(stream, Cb, conv0_W + HH, nullptr, B_, N, HDIM, HDIM, HDIM, true, false);
    hipMemsetAsync(Db, 0, NH * 4, stream);
    spmm_scatter_k<<<sg, sb, 0, stream>>>(Cb, srcI, dstI, ew, Db, E);
    gemm(stream, Db, conv0_W + 2 * HH, nullptr, B_, N, HDIM, HDIM, HDIM, true, false);

    float* hb = B_;   // h lives here across layers

    for (int l = 0; l < 3; ++l) {
        const float* Wl = conv_W + (size_t)l * 3 * HH;

        // z = leaky(bn(h)) -> A_
        hipMemsetAsync(stats, 0, 512 * 4, stream);
        colstats_k<<<dim3(256), dim3(256), 0, stream>>>(hb, stats, N);
        finalize_k<<<dim3(1), dim3(256), 0, stream>>>(stats, norm_g + l * HDIM, norm_b + l * HDIM, ab, invn);
        apply_bn_leaky_k<<<ag, abk, 0, stream>>>(hb, ab, A_, n4);

        // conv: Cb = z@W0 + b ; + (A.z)@W1 ; + (A^2.z)@W2
        gemm(stream, A_, Wl, conv_b + l * HDIM, Cb, N, HDIM, HDIM, HDIM, false, true);
        hipMemsetAsync(Db, 0, NH * 4, stream);
        spmm_scatter_k<<<sg, sb, 0, stream>>>(A_, srcI, dstI, ew, Db, E);
        gemm(stream, Db, Wl + HH, nullptr, Cb, N, HDIM, HDIM, HDIM, true, false);
        hipMemsetAsync(A_, 0, NH * 4, stream);
        spmm_scatter_k<<<sg, sb, 0, stream>>>(Db, srcI, dstI, ew, A_, E);
        gemm(stream, A_, Wl + 2 * HH, nullptr, Cb, N, HDIM, HDIM, HDIM, true, false);

        // MLP chunked over 4 blocks of 256 hidden cols; h += leaky(bn(Cb@W1+b1))@W2 (+b2 once)
        for (int blk = 0; blk < 4; ++blk) {
            gemm(stream, Cb, mlp_W1 + (size_t)l * HDIM * 1024 + blk * HDIM,
                 mlp_b1 + (size_t)l * 1024 + blk * HDIM, Db, N, HDIM, HDIM, 1024, false, true);
            hipMemsetAsync(stats, 0, 512 * 4, stream);
            colstats_k<<<dim3(256), dim3(256), 0, stream>>>(Db, stats, N);
            finalize_k<<<dim3(1), dim3(256), 0, stream>>>(stats, mlp_g + (size_t)l * 1024 + blk * HDIM,
                                                          mlp_bb + (size_t)l * 1024 + blk * HDIM, ab, invn);
            apply_bn_leaky_k<<<ag, abk, 0, stream>>>(Db, ab, Db, n4);
            gemm(stream, Db, mlp_W2 + (size_t)l * 1024 * HDIM + (size_t)blk * HDIM * HDIM,
                 mlp_b2 + l * HDIM, hb, N, HDIM, HDIM, HDIM, true, blk == 0);
        }
    }

    // out = h @ W_out + b_out
    gemm(stream, hb, W_out, b_out, (float*)d_out, N, HDIM, 128, 128, false, true);
}

// Round 3
// 6389.866 us; speedup vs baseline: 4.2353x; 4.2353x over previous
//
#include <hip/hip_runtime.h>

#define HDIM 256
#define EPSV 1e-5f
#define SLOPEV 0.01f

// ---------------- GEMM: C[n x m] = (ADD?C:0) + A[n x k] * W[k x m](ld ldw) + (BIAS?bias:0)
template<bool ADD, bool BIAS>
__global__ __launch_bounds__(256)
void gemm_k(const float* __restrict__ A, const float* __restrict__ W,
            const float* __restrict__ bias, float* __restrict__ C,
            int n, int k, int m, int ldw)
{
    __shared__ float As[16][68];
    __shared__ float Ws[16][68];
    const int tid = threadIdx.x;
    const int bm = blockIdx.y * 64;   // row base
    const int bn = blockIdx.x * 64;   // col base
    const int ty = tid >> 4, tx = tid & 15;
    float acc[4][4] = {};

    for (int kt = 0; kt < k; kt += 16) {
        {
            int r  = tid >> 2;
            int kk = (tid & 3) * 4;
            int row = bm + r;
            float4 v = make_float4(0.f, 0.f, 0.f, 0.f);
            if (row < n) v = *(const float4*)(A + (size_t)row * k + kt + kk);
            As[kk + 0][r] = v.x; As[kk + 1][r] = v.y;
            As[kk + 2][r] = v.z; As[kk + 3][r] = v.w;
        }
        {
            int kk = tid >> 4;
            int c  = (tid & 15) * 4;
            float4 v = *(const float4*)(W + (size_t)(kt + kk) * ldw + bn + c);
            *(float4*)(&Ws[kk][c]) = v;
        }
        __syncthreads();
#pragma unroll
        for (int kk = 0; kk < 16; ++kk) {
            float a0 = As[kk][ty * 4 + 0], a1 = As[kk][ty * 4 + 1];
            float a2 = As[kk][ty * 4 + 2], a3 = As[kk][ty * 4 + 3];
            float w0 = Ws[kk][tx * 4 + 0], w1 = Ws[kk][tx * 4 + 1];
            float w2 = Ws[kk][tx * 4 + 2], w3 = Ws[kk][tx * 4 + 3];
            acc[0][0] += a0 * w0; acc[0][1] += a0 * w1; acc[0][2] += a0 * w2; acc[0][3] += a0 * w3;
            acc[1][0] += a1 * w0; acc[1][1] += a1 * w1; acc[1][2] += a1 * w2; acc[1][3] += a1 * w3;
            acc[2][0] += a2 * w0; acc[2][1] += a2 * w1; acc[2][2] += a2 * w2; acc[2][3] += a2 * w3;
            acc[3][0] += a3 * w0; acc[3][1] += a3 * w1; acc[3][2] += a3 * w2; acc[3][3] += a3 * w3;
        }
        __syncthreads();
    }

    float4 bv = make_float4(0.f, 0.f, 0.f, 0.f);
    if (BIAS) bv = *(const float4*)(bias + bn + tx * 4);
#pragma unroll
    for (int i = 0; i < 4; ++i) {
        int row = bm + ty * 4 + i;
        if (row >= n) break;
        float* cp = C + (size_t)row * m + bn + tx * 4;
        float4 r = make_float4(acc[i][0], acc[i][1], acc[i][2], acc[i][3]);
        if (BIAS) { r.x += bv.x; r.y += bv.y; r.z += bv.z; r.w += bv.w; }
        if (ADD) {
            float4 o = *(const float4*)cp;
            r.x += o.x; r.y += o.y; r.z += o.z; r.w += o.w;
        }
        *(float4*)cp = r;
    }
}

// ---------------- CSR build ----------------
__global__ __launch_bounds__(256)
void deg_k(const int* __restrict__ dst, int* __restrict__ deg, int E)
{
    int e = blockIdx.x * blockDim.x + threadIdx.x;
    if (e < E) atomicAdd(&deg[dst[e]], 1);
}

// single block, 1024 threads: rowptr = exclusive scan of deg (rowptr[0]=0, len N+1)
__global__ __launch_bounds__(1024)
void scan_k(const int* __restrict__ deg, int* __restrict__ rowptr, int N)
{
    __shared__ int s[1024];
    const int tid = threadIdx.x;
    if (tid == 0) rowptr[0] = 0;
    int running = 0;
    for (int base = 0; base < N; base += 1024) {
        int i = base + tid;
        int x = (i < N) ? deg[i] : 0;
        s[tid] = x;
        __syncthreads();
        for (int off = 1; off < 1024; off <<= 1) {
            int t = (tid >= off) ? s[tid - off] : 0;
            __syncthreads();
            s[tid] += t;
            __syncthreads();
        }
        if (i < N) rowptr[i + 1] = s[tid] + running;
        running += s[1023];
        __syncthreads();
    }
}

__global__ __launch_bounds__(256)
void reorder_k(const int* __restrict__ src, const int* __restrict__ dst,
               const float* __restrict__ ew, int* __restrict__ wp,
               int* __restrict__ col, float* __restrict__ wgt, int E)
{
    int e = blockIdx.x * blockDim.x + threadIdx.x;
    if (e >= E) return;
    int d = dst[e];
    int pos = atomicAdd(&wp[d], 1);
    col[pos] = src[e];
    wgt[pos] = ew[e];
}

// ---------------- pull SpMM: Q[v] = sum_{e in row v} wgt[e] * P[col[e]]  (wave per node)
__global__ __launch_bounds__(256)
void spmm_pull_k(const float* __restrict__ P, const int* __restrict__ rowptr,
                 const int* __restrict__ col, const float* __restrict__ wgt,
                 float* __restrict__ Q, int N)
{
    int node = blockIdx.x * 4 + (threadIdx.x >> 6);
    int lane = threadIdx.x & 63;
    if (node >= N) return;
    int e   = rowptr[node];
    int end = rowptr[node + 1];
    float4 acc = make_float4(0.f, 0.f, 0.f, 0.f);
    for (; e + 1 < end; e += 2) {
        int   s0 = col[e],     s1 = col[e + 1];
        float w0 = wgt[e],     w1 = wgt[e + 1];
        float4 v0 = *(const float4*)(P + (size_t)s0 * HDIM + lane * 4);
        float4 v1 = *(const float4*)(P + (size_t)s1 * HDIM + lane * 4);
        acc.x += v0.x * w0 + v1.x * w1;
        acc.y += v0.y * w0 + v1.y * w1;
        acc.z += v0.z * w0 + v1.z * w1;
        acc.w += v0.w * w0 + v1.w * w1;
    }
    if (e < end) {
        int s0 = col[e]; float w0 = wgt[e];
        float4 v0 = *(const float4*)(P + (size_t)s0 * HDIM + lane * 4);
        acc.x += v0.x * w0; acc.y += v0.y * w0; acc.z += v0.z * w0; acc.w += v0.w * w0;
    }
    *(float4*)(Q + (size_t)node * HDIM + lane * 4) = acc;
}

// ---------------- column stats ----------------
__global__ __launch_bounds__(256)
void colstats_k(const float* __restrict__ X, float* __restrict__ sums, int n)
{
    int c = threadIdx.x;
    float s = 0.f, s2 = 0.f;
    for (int r = blockIdx.x; r < n; r += gridDim.x) {
        float v = X[(size_t)r * HDIM + c];
        s += v; s2 += v * v;
    }
    unsafeAtomicAdd(&sums[c], s);
    unsafeAtomicAdd(&sums[HDIM + c], s2);
}

__global__ __launch_bounds__(256)
void finalize_k(const float* __restrict__ sums, const float* __restrict__ g,
                const float* __restrict__ b, float* __restrict__ ab, float invn)
{
    int c = threadIdx.x;
    float mean = sums[c] * invn;
    float var  = sums[HDIM + c] * invn - mean * mean;
    float a = g[c] * rsqrtf(var + EPSV);
    ab[c]        = a;
    ab[HDIM + c] = b[c] - mean * a;
}

__global__ __launch_bounds__(256)
void apply_bn_leaky_k(const float* __restrict__ X, const float* __restrict__ ab,
                      float* __restrict__ Y, long n4)
{
    long i0 = (long)blockIdx.x * blockDim.x + threadIdx.x;
    long stride = (long)gridDim.x * blockDim.x;
    for (long i = i0; i < n4; i += stride) {
        float4 v = ((const float4*)X)[i];
        int c4 = (int)(i & 63);
        float4 a = ((const float4*)ab)[c4];
        float4 b = ((const float4*)(ab + HDIM))[c4];
        float4 r;
        r.x = fmaf(v.x, a.x, b.x); r.x = r.x > 0.f ? r.x : SLOPEV * r.x;
        r.y = fmaf(v.y, a.y, b.y); r.y = r.y > 0.f ? r.y : SLOPEV * r.y;
        r.z = fmaf(v.z, a.z, b.z); r.z = r.z > 0.f ? r.z : SLOPEV * r.z;
        r.w = fmaf(v.w, a.w, b.w); r.w = r.w > 0.f ? r.w : SLOPEV * r.w;
        ((float4*)Y)[i] = r;
    }
}

// ================= host orchestration =================
static void gemm(hipStream_t st, const float* A, const float* W, const float* bias,
                 float* C, int n, int k, int m, int ldw, bool add, bool biasb)
{
    dim3 g(m / 64, (n + 63) / 64), b(256);
    if (add) {
        if (biasb) gemm_k<true, true><<<g, b, 0, st>>>(A, W, bias, C, n, k, m, ldw);
        else       gemm_k<true, false><<<g, b, 0, st>>>(A, W, bias, C, n, k, m, ldw);
    } else {
        if (biasb) gemm_k<false, true><<<g, b, 0, st>>>(A, W, bias, C, n, k, m, ldw);
        else       gemm_k<false, false><<<g, b, 0, st>>>(A, W, bias, C, n, k, m, ldw);
    }
}

extern "C" void kernel_launch(void* const* d_in, const int* in_sizes, int n_in,
                              void* d_out, int out_size, void* d_ws, size_t ws_size,
                              hipStream_t stream)
{
    const float* x       = (const float*)d_in[0];
    const int*   ei      = (const int*)d_in[1];
    const float* ew      = (const float*)d_in[2];
    const float* W_emb   = (const float*)d_in[3];
    const float* b_emb   = (const float*)d_in[4];
    const float* conv0_W = (const float*)d_in[5];
    const float* conv0_b = (const float*)d_in[6];
    const float* norm_g  = (const float*)d_in[7];
    const float* norm_b  = (const float*)d_in[8];
    const float* conv_W  = (const float*)d_in[9];
    const float* conv_b  = (const float*)d_in[10];
    const float* mlp_W1  = (const float*)d_in[11];
    const float* mlp_b1  = (const float*)d_in[12];
    const float* mlp_g   = (const float*)d_in[13];
    const float* mlp_bb  = (const float*)d_in[14];
    const float* mlp_W2  = (const float*)d_in[15];
    const float* mlp_b2  = (const float*)d_in[16];
    const float* W_out   = (const float*)d_in[17];
    const float* b_out   = (const float*)d_in[18];

    const int N = in_sizes[0] / 128;          // 50000
    const int E = in_sizes[2];                // 800000
    const int* srcI = ei;
    const int* dstI = ei + E;

    const size_t NH = (size_t)N * HDIM;
    float* A_ = (float*)d_ws;
    float* B_ = A_ + NH;
    float* Cb = B_ + NH;
    float* Db = Cb + NH;
    float* stats = Db + NH;       // 512 floats
    float* ab    = stats + 512;   // 512 floats
    int*   rowptr = (int*)(ab + 512);       // N+1
    int*   wp     = rowptr + (N + 1);       // N (deg, then write-ptr)
    int*   col    = wp + N;                 // E
    float* wgt    = (float*)(col + E);      // E

    const size_t HH = (size_t)HDIM * HDIM;
    const long n4 = (long)NH / 4;
    dim3 ag(12544), abk(256);
    dim3 pg((N + 3) / 4), pb(256);
    const float invn = 1.0f / (float)N;

    // ---- build CSR (dst-sorted) once; reused by all 8 propagations ----
    hipMemsetAsync(wp, 0, (size_t)N * 4, stream);
    deg_k<<<dim3((E + 255) / 256), dim3(256), 0, stream>>>(dstI, wp, E);
    scan_k<<<dim3(1), dim3(1024), 0, stream>>>(wp, rowptr, N);
    hipMemcpyAsync(wp, rowptr, (size_t)N * 4, hipMemcpyDeviceToDevice, stream);
    reorder_k<<<dim3((E + 255) / 256), dim3(256), 0, stream>>>(srcI, dstI, ew, wp, col, wgt, E);

    // h = x @ W_emb + b_emb -> A_
    gemm(stream, x, W_emb, b_emb, A_, N, 128, HDIM, HDIM, false, true);

    // conv0: B_ = A_@W0 + b ; + (A.A_)@W1 ; + (A^2.A_)@W2
    gemm(stream, A_, conv0_W, conv0_b, B_, N, HDIM, HDIM, HDIM, false, true);
    spmm_pull_k<<<pg, pb, 0, stream>>>(A_, rowptr, col, wgt, Cb, N);
    gemm(stream, Cb, conv0_W + HH, nullptr, B_, N, HDIM, HDIM, HDIM, true, false);
    spmm_pull_k<<<pg, pb, 0, stream>>>(Cb, rowptr, col, wgt, Db, N);
    gemm(stream, Db, conv0_W + 2 * HH, nullptr, B_, N, HDIM, HDIM, HDIM, true, false);

    float* hb = B_;   // h lives here across layers

    for (int l = 0; l < 3; ++l) {
        const float* Wl = conv_W + (size_t)l * 3 * HH;

        // z = leaky(bn(h)) -> A_
        hipMemsetAsync(stats, 0, 512 * 4, stream);
        colstats_k<<<dim3(256), dim3(256), 0, stream>>>(hb, stats, N);
        finalize_k<<<dim3(1), dim3(256), 0, stream>>>(stats, norm_g + l * HDIM, norm_b + l * HDIM, ab, invn);
        apply_bn_leaky_k<<<ag, abk, 0, stream>>>(hb, ab, A_, n4);

        // conv: Cb = z@W0 + b ; + (A.z)@W1 ; + (A^2.z)@W2
        gemm(stream, A_, Wl, conv_b + l * HDIM, Cb, N, HDIM, HDIM, HDIM, false, true);
        spmm_pull_k<<<pg, pb, 0, stream>>>(A_, rowptr, col, wgt, Db, N);
        gemm(stream, Db, Wl + HH, nullptr, Cb, N, HDIM, HDIM, HDIM, true, false);
        spmm_pull_k<<<pg, pb, 0, stream>>>(Db, rowptr, col, wgt, A_, N);
        gemm(stream, A_, Wl + 2 * HH, nullptr, Cb, N, HDIM, HDIM, HDIM, true, false);

        // MLP chunked over 4 blocks of 256 hidden cols; h += leaky(bn(Cb@W1+b1))@W2 (+b2 once)
        for (int blk = 0; blk < 4; ++blk) {
            gemm(stream, Cb, mlp_W1 + (size_t)l * HDIM * 1024 + blk * HDIM,
                 mlp_b1 + (size_t)l * 1024 + blk * HDIM, Db, N, HDIM, HDIM, 1024, false, true);
            hipMemsetAsync(stats, 0, 512 * 4, stream);
            colstats_k<<<dim3(256), dim3(256), 0, stream>>>(Db, stats, N);
            finalize_k<<<dim3(1), dim3(256), 0, stream>>>(stats, mlp_g + (size_t)l * 1024 + blk * HDIM,
                                                          mlp_bb + (size_t)l * 1024 + blk * HDIM, ab, invn);
            apply_bn_leaky_k<<<ag, abk, 0, stream>>>(Db, ab, Db, n4);
            gemm(stream, Db, mlp_W2 + (size_t)l * 1024 * HDIM + (size_t)blk * HDIM * HDIM,
                 mlp_b2 + l * HDIM, hb, N, HDIM, HDIM, HDIM, true, blk == 0);
        }
    }

    // out = h @ W_out + b_out
    gemm(stream, hb, W_out, b_out, (float*)d_out, N, HDIM, 128, 128, false, true);
}

// Round 4
// 4027.737 us; speedup vs baseline: 6.7192x; 1.5865x over previous
//
#include <hip/hip_runtime.h>

#define HDIM 256
#define EPSV 1e-5f
#define SLOPEV 0.01f

typedef __bf16 bf16;
typedef bf16  bf16x8 __attribute__((ext_vector_type(8)));
typedef bf16  bf16x4 __attribute__((ext_vector_type(4)));
typedef float f32x4  __attribute__((ext_vector_type(4)));

#define GLD16(g, l) __builtin_amdgcn_global_load_lds( \
    (const __attribute__((address_space(1))) void*)(g), \
    (__attribute__((address_space(3))) void*)(l), 16, 0, 0)

// ================= MFMA GEMM: out[n x M] = A[n x K](bf16) * Wt[M x K]^T (bf16)
//                  + bias + addf(f32) + addb(bf16); store bf16 or f32
template<bool STORE_BF16>
__global__ __launch_bounds__(256)
void gemm_bt_k(const bf16* __restrict__ A, const bf16* __restrict__ Wt, int ldw,
               const float* __restrict__ bias,
               const float* __restrict__ addf, const bf16* __restrict__ addb,
               void* __restrict__ out, int ldo, int K, int n_store)
{
    __shared__ bf16 As[128 * 32];   // row-major [m][k], 8 KB
    __shared__ bf16 Bs[128 * 32];   // row-major [n][k], 8 KB
    const int tid  = threadIdx.x;
    const int wave = tid >> 6, lane = tid & 63;
    const int quad = lane >> 4, l16 = lane & 15;
    const int waveM = (wave >> 1) * 64, waveN = (wave & 1) * 64;
    const int bm = blockIdx.y * 128, bn = blockIdx.x * 128;

    // staging: chunk = c*256 + tid; row = chunk>>2; 16B piece (chunk&3) of the 64B k-row
    const char* gA0 = (const char*)(A  + (size_t)(bm + (tid >> 2)) * K   + (tid & 3) * 8);
    const char* gA1 = (const char*)(A  + (size_t)(bm + 64 + (tid >> 2)) * K + (tid & 3) * 8);
    const char* gB0 = (const char*)(Wt + (size_t)(bn + (tid >> 2)) * ldw + (tid & 3) * 8);
    const char* gB1 = (const char*)(Wt + (size_t)(bn + 64 + (tid >> 2)) * ldw + (tid & 3) * 8);
    char* lA0 = (char*)As + wave * 1024;
    char* lA1 = (char*)As + 4096 + wave * 1024;
    char* lB0 = (char*)Bs + wave * 1024;
    char* lB1 = (char*)Bs + 4096 + wave * 1024;

    f32x4 acc[4][4] = {};
    const bf16* pa = As + (waveM + l16) * 32 + quad * 8;
    const bf16* pb = Bs + (waveN + l16) * 32 + quad * 8;

    for (int kt = 0; kt < K; kt += 32) {
        GLD16(gA0, lA0); GLD16(gA1, lA1);
        GLD16(gB0, lB0); GLD16(gB1, lB1);
        gA0 += 64; gA1 += 64; gB0 += 64; gB1 += 64;
        __syncthreads();

        bf16x8 a0 = *(const bf16x8*)(pa);
        bf16x8 a1 = *(const bf16x8*)(pa + 16 * 32);
        bf16x8 a2 = *(const bf16x8*)(pa + 32 * 32);
        bf16x8 a3 = *(const bf16x8*)(pa + 48 * 32);
        bf16x8 b0 = *(const bf16x8*)(pb);
        bf16x8 b1 = *(const bf16x8*)(pb + 16 * 32);
        bf16x8 b2 = *(const bf16x8*)(pb + 32 * 32);
        bf16x8 b3 = *(const bf16x8*)(pb + 48 * 32);

        acc[0][0] = __builtin_amdgcn_mfma_f32_16x16x32_bf16(a0, b0, acc[0][0], 0, 0, 0);
        acc[0][1] = __builtin_amdgcn_mfma_f32_16x16x32_bf16(a0, b1, acc[0][1], 0, 0, 0);
        acc[0][2] = __builtin_amdgcn_mfma_f32_16x16x32_bf16(a0, b2, acc[0][2], 0, 0, 0);
        acc[0][3] = __builtin_amdgcn_mfma_f32_16x16x32_bf16(a0, b3, acc[0][3], 0, 0, 0);
        acc[1][0] = __builtin_amdgcn_mfma_f32_16x16x32_bf16(a1, b0, acc[1][0], 0, 0, 0);
        acc[1][1] = __builtin_amdgcn_mfma_f32_16x16x32_bf16(a1, b1, acc[1][1], 0, 0, 0);
        acc[1][2] = __builtin_amdgcn_mfma_f32_16x16x32_bf16(a1, b2, acc[1][2], 0, 0, 0);
        acc[1][3] = __builtin_amdgcn_mfma_f32_16x16x32_bf16(a1, b3, acc[1][3], 0, 0, 0);
        acc[2][0] = __builtin_amdgcn_mfma_f32_16x16x32_bf16(a2, b0, acc[2][0], 0, 0, 0);
        acc[2][1] = __builtin_amdgcn_mfma_f32_16x16x32_bf16(a2, b1, acc[2][1], 0, 0, 0);
        acc[2][2] = __builtin_amdgcn_mfma_f32_16x16x32_bf16(a2, b2, acc[2][2], 0, 0, 0);
        acc[2][3] = __builtin_amdgcn_mfma_f32_16x16x32_bf16(a2, b3, acc[2][3], 0, 0, 0);
        acc[3][0] = __builtin_amdgcn_mfma_f32_16x16x32_bf16(a3, b0, acc[3][0], 0, 0, 0);
        acc[3][1] = __builtin_amdgcn_mfma_f32_16x16x32_bf16(a3, b1, acc[3][1], 0, 0, 0);
        acc[3][2] = __builtin_amdgcn_mfma_f32_16x16x32_bf16(a3, b2, acc[3][2], 0, 0, 0);
        acc[3][3] = __builtin_amdgcn_mfma_f32_16x16x32_bf16(a3, b3, acc[3][3], 0, 0, 0);
        __syncthreads();
    }

    float bv[4];
#pragma unroll
    for (int j = 0; j < 4; ++j)
        bv[j] = bias ? bias[bn + waveN + j * 16 + l16] : 0.f;

#pragma unroll
    for (int i = 0; i < 4; ++i) {
#pragma unroll
        for (int j = 0; j < 4; ++j) {
            int colg = bn + waveN + j * 16 + l16;
#pragma unroll
            for (int r = 0; r < 4; ++r) {
                int rowg = bm + waveM + i * 16 + quad * 4 + r;
                if (rowg < n_store) {
                    size_t idx = (size_t)rowg * ldo + colg;
                    float v = acc[i][j][r] + bv[j];
                    if (addf) v += addf[idx];
                    if (addb) v += (float)addb[idx];
                    if (STORE_BF16) ((bf16*)out)[idx] = (bf16)v;
                    else            ((float*)out)[idx] = v;
                }
            }
        }
    }
}

// ================= transpose+convert: dst[m*K+k] = (bf16)src[k*M+m], batched over z
__global__ __launch_bounds__(256)
void transpose_cvt_k(const float* __restrict__ src, bf16* __restrict__ dst, int K, int M)
{
    __shared__ float t[32][33];
    const size_t bo = (size_t)blockIdx.z * K * M;
    src += bo; dst += bo;
    const int tM = blockIdx.x * 32, tK = blockIdx.y * 32;
    const int tx = threadIdx.x & 31, ty = threadIdx.x >> 5;
#pragma unroll
    for (int r = 0; r < 4; ++r)
        t[ty + r * 8][tx] = src[(size_t)(tK + ty + r * 8) * M + tM + tx];
    __syncthreads();
#pragma unroll
    for (int r = 0; r < 4; ++r)
        dst[(size_t)(tM + ty + r * 8) * K + tK + tx] = (bf16)t[tx][ty + r * 8];
}

// ================= x f32 -> bf16
__global__ __launch_bounds__(256)
void cvt_bf_k(const float* __restrict__ src, bf16* __restrict__ dst, long n4)
{
    long i = (long)blockIdx.x * blockDim.x + threadIdx.x;
    if (i >= n4) return;
    float4 v = ((const float4*)src)[i];
    bf16x4 o; o[0] = (bf16)v.x; o[1] = (bf16)v.y; o[2] = (bf16)v.z; o[3] = (bf16)v.w;
    ((bf16x4*)dst)[i] = o;
}

// ================= CSR build =================
__global__ __launch_bounds__(256)
void deg_k(const int* __restrict__ dst, int* __restrict__ deg, int E)
{
    int e = blockIdx.x * blockDim.x + threadIdx.x;
    if (e < E) atomicAdd(&deg[dst[e]], 1);
}

__global__ __launch_bounds__(1024)
void scan_k(const int* __restrict__ deg, int* __restrict__ rowptr, int N)
{
    __shared__ int s[1024];
    const int tid = threadIdx.x;
    if (tid == 0) rowptr[0] = 0;
    int running = 0;
    for (int base = 0; base < N; base += 1024) {
        int i = base + tid;
        int x = (i < N) ? deg[i] : 0;
        s[tid] = x;
        __syncthreads();
        for (int off = 1; off < 1024; off <<= 1) {
            int t = (tid >= off) ? s[tid - off] : 0;
            __syncthreads();
            s[tid] += t;
            __syncthreads();
        }
        if (i < N) rowptr[i + 1] = s[tid] + running;
        running += s[1023];
        __syncthreads();
    }
}

__global__ __launch_bounds__(256)
void reorder_k(const int* __restrict__ src, const int* __restrict__ dst,
               const float* __restrict__ ew, int* __restrict__ wp,
               int* __restrict__ col, float* __restrict__ wgt, int E)
{
    int e = blockIdx.x * blockDim.x + threadIdx.x;
    if (e >= E) return;
    int d = dst[e];
    int pos = atomicAdd(&wp[d], 1);
    col[pos] = src[e];
    wgt[pos] = ew[e];
}

// ================= pull SpMM (bf16 features, fp32 accum)
__global__ __launch_bounds__(256)
void spmm_pull_k(const bf16* __restrict__ P, const int* __restrict__ rowptr,
                 const int* __restrict__ col, const float* __restrict__ wgt,
                 bf16* __restrict__ Q, int N)
{
    int node = blockIdx.x * 4 + (threadIdx.x >> 6);
    int lane = threadIdx.x & 63;
    if (node >= N) return;
    int e = rowptr[node], end = rowptr[node + 1];
    float ax = 0.f, ay = 0.f, az = 0.f, aw = 0.f;
    for (; e < end; ++e) {
        int s = col[e];
        float w = wgt[e];
        bf16x4 v = *(const bf16x4*)(P + (size_t)s * HDIM + lane * 4);
        ax += (float)v[0] * w; ay += (float)v[1] * w;
        az += (float)v[2] * w; aw += (float)v[3] * w;
    }
    bf16x4 o; o[0] = (bf16)ax; o[1] = (bf16)ay; o[2] = (bf16)az; o[3] = (bf16)aw;
    *(bf16x4*)(Q + (size_t)node * HDIM + lane * 4) = o;
}

// ================= BN =================
__global__ __launch_bounds__(256)
void colstats_k(const bf16* __restrict__ X, float* __restrict__ sums, int n)
{
    int c = threadIdx.x;
    float s = 0.f, s2 = 0.f;
    for (int r = blockIdx.x; r < n; r += gridDim.x) {
        float v = (float)X[(size_t)r * HDIM + c];
        s += v; s2 += v * v;
    }
    unsafeAtomicAdd(&sums[c], s);
    unsafeAtomicAdd(&sums[HDIM + c], s2);
}

__global__ __launch_bounds__(256)
void finalize_k(const float* __restrict__ sums, const float* __restrict__ g,
                const float* __restrict__ b, float* __restrict__ ab, float invn)
{
    int c = threadIdx.x;
    float mean = sums[c] * invn;
    float var  = sums[HDIM + c] * invn - mean * mean;
    float a = g[c] * rsqrtf(var + EPSV);
    ab[c]        = a;
    ab[HDIM + c] = b[c] - mean * a;
}

__global__ __launch_bounds__(256)
void apply_bn_leaky_k(const bf16* __restrict__ X, const float* __restrict__ ab,
                      bf16* __restrict__ Y, long n4)
{
    long i0 = (long)blockIdx.x * blockDim.x + threadIdx.x;
    long stride = (long)gridDim.x * blockDim.x;
    for (long i = i0; i < n4; i += stride) {
        bf16x4 v = ((const bf16x4*)X)[i];
        int c4 = (int)(i & 63);
        float4 a = ((const float4*)ab)[c4];
        float4 b = ((const float4*)(ab + HDIM))[c4];
        float r0 = fmaf((float)v[0], a.x, b.x); r0 = r0 > 0.f ? r0 : SLOPEV * r0;
        float r1 = fmaf((float)v[1], a.y, b.y); r1 = r1 > 0.f ? r1 : SLOPEV * r1;
        float r2 = fmaf((float)v[2], a.z, b.z); r2 = r2 > 0.f ? r2 : SLOPEV * r2;
        float r3 = fmaf((float)v[3], a.w, b.w); r3 = r3 > 0.f ? r3 : SLOPEV * r3;
        bf16x4 o; o[0] = (bf16)r0; o[1] = (bf16)r1; o[2] = (bf16)r2; o[3] = (bf16)r3;
        ((bf16x4*)Y)[i] = o;
    }
}

// ================= host orchestration =================
static void gemm(hipStream_t st, const bf16* A, const bf16* Wt, int ldw, const float* bias,
                 const float* addf, const bf16* addb, void* out, int ldo, int K, int M,
                 int n_store, bool store_bf16, int grid_y)
{
    dim3 g(M / 128, grid_y), b(256);
    if (store_bf16)
        gemm_bt_k<true><<<g, b, 0, st>>>(A, Wt, ldw, bias, addf, addb, out, ldo, K, n_store);
    else
        gemm_bt_k<false><<<g, b, 0, st>>>(A, Wt, ldw, bias, addf, addb, out, ldo, K, n_store);
}

extern "C" void kernel_launch(void* const* d_in, const int* in_sizes, int n_in,
                              void* d_out, int out_size, void* d_ws, size_t ws_size,
                              hipStream_t stream)
{
    const float* x       = (const float*)d_in[0];
    const int*   ei      = (const int*)d_in[1];
    const float* ew      = (const float*)d_in[2];
    const float* W_emb   = (const float*)d_in[3];
    const float* b_emb   = (const float*)d_in[4];
    const float* conv0_W = (const float*)d_in[5];
    const float* conv0_b = (const float*)d_in[6];
    const float* norm_g  = (const float*)d_in[7];
    const float* norm_b  = (const float*)d_in[8];
    const float* conv_W  = (const float*)d_in[9];
    const float* conv_b  = (const float*)d_in[10];
    const float* mlp_W1  = (const float*)d_in[11];
    const float* mlp_b1  = (const float*)d_in[12];
    const float* mlp_g   = (const float*)d_in[13];
    const float* mlp_bb  = (const float*)d_in[14];
    const float* mlp_W2  = (const float*)d_in[15];
    const float* mlp_b2  = (const float*)d_in[16];
    const float* W_out   = (const float*)d_in[17];
    const float* b_out   = (const float*)d_in[18];

    const int N = in_sizes[0] / 128;          // 50000
    const int E = in_sizes[2];                // 800000
    const int* srcI = ei;
    const int* dstI = ei + E;
    const int N_pad = ((N + 127) / 128) * 128;   // 50048
    const int GY = N_pad / 128;                  // 391

    const size_t NHp = (size_t)N_pad * HDIM;
    float* Cacc = (float*)d_ws;                  // NHp f32 (conv acc / mlp residual acc)
    bf16*  hb   = (bf16*)(Cacc + NHp);
    bf16*  zb   = hb + NHp;                      // BN out / conv out
    bf16*  p1   = zb + NHp;                      // hop-1 / mlp hidden chunk
    bf16*  p2   = p1 + NHp;                      // hop-2
    bf16*  xb   = p2 + NHp;                      // N_pad x 128
    bf16*  wa   = xb + (size_t)N_pad * 128;      // weight arena, 2424832 bf16
    bf16*  Wt_emb   = wa;
    bf16*  Wt_conv0 = wa + 32768;
    bf16*  Wt_conv  = wa + 229376;
    bf16*  Wt_mlp1  = wa + 819200;
    bf16*  Wt_mlp2  = wa + 1605632;
    bf16*  Wt_out   = wa + 2392064;
    float* stats  = (float*)(wa + 2424832);
    float* ab     = stats + 512;
    int*   rowptr = (int*)(ab + 512);
    int*   wp     = rowptr + (N + 1);
    int*   col    = wp + N;
    float* wgt    = (float*)(col + E);

    const size_t HH = (size_t)HDIM * HDIM;
    const long n4 = (long)N * 64;   // N*256/4 bf16x4 groups
    dim3 ag(12544), abk(256);
    dim3 pg((N + 3) / 4), pb(256);
    const float invn = 1.0f / (float)N;

    // ---- CSR build (dst-sorted) ----
    hipMemsetAsync(wp, 0, (size_t)N * 4, stream);
    deg_k<<<dim3((E + 255) / 256), dim3(256), 0, stream>>>(dstI, wp, E);
    scan_k<<<dim3(1), dim3(1024), 0, stream>>>(wp, rowptr, N);
    hipMemcpyAsync(wp, rowptr, (size_t)N * 4, hipMemcpyDeviceToDevice, stream);
    reorder_k<<<dim3((E + 255) / 256), dim3(256), 0, stream>>>(srcI, dstI, ew, wp, col, wgt, E);

    // ---- convert inputs/weights to bf16 ----
    cvt_bf_k<<<dim3((N * 32 + 255) / 256), dim3(256), 0, stream>>>(x, xb, (long)N * 32);
    transpose_cvt_k<<<dim3(8, 4, 1), dim3(256), 0, stream>>>(W_emb, Wt_emb, 128, 256);
    transpose_cvt_k<<<dim3(8, 8, 3), dim3(256), 0, stream>>>(conv0_W, Wt_conv0, 256, 256);
    transpose_cvt_k<<<dim3(8, 8, 9), dim3(256), 0, stream>>>(conv_W, Wt_conv, 256, 256);
    transpose_cvt_k<<<dim3(32, 8, 3), dim3(256), 0, stream>>>(mlp_W1, Wt_mlp1, 256, 1024);
    transpose_cvt_k<<<dim3(8, 32, 3), dim3(256), 0, stream>>>(mlp_W2, Wt_mlp2, 1024, 256);
    transpose_cvt_k<<<dim3(4, 8, 1), dim3(256), 0, stream>>>(W_out, Wt_out, 256, 128);

    // ---- embed: zb = bf16(x @ W_emb + b_emb) ----
    gemm(stream, xb, Wt_emb, 128, b_emb, nullptr, nullptr, zb, HDIM, 128, 256, N_pad, true, GY);

    // ---- conv0: hb = bf16( zb@W0 + (A zb)@W1 + (A^2 zb)@W2 + b ) ----
    gemm(stream, zb, Wt_conv0, 256, conv0_b, nullptr, nullptr, Cacc, HDIM, 256, 256, N_pad, false, GY);
    spmm_pull_k<<<pg, pb, 0, stream>>>(zb, rowptr, col, wgt, p1, N);
    gemm(stream, p1, Wt_conv0 + HH, 256, nullptr, Cacc, nullptr, Cacc, HDIM, 256, 256, N_pad, false, GY);
    spmm_pull_k<<<pg, pb, 0, stream>>>(p1, rowptr, col, wgt, p2, N);
    gemm(stream, p2, Wt_conv0 + 2 * HH, 256, nullptr, Cacc, nullptr, hb, HDIM, 256, 256, N_pad, true, GY);

    for (int l = 0; l < 3; ++l) {
        const bf16* Wl = Wt_conv + (size_t)l * 3 * HH;

        // zb = leaky(bn(hb))
        hipMemsetAsync(stats, 0, 512 * 4, stream);
        colstats_k<<<dim3(256), dim3(256), 0, stream>>>(hb, stats, N);
        finalize_k<<<dim3(1), dim3(256), 0, stream>>>(stats, norm_g + l * HDIM, norm_b + l * HDIM, ab, invn);
        apply_bn_leaky_k<<<ag, abk, 0, stream>>>(hb, ab, zb, n4);

        // conv -> zb (bf16), partials in Cacc (f32)
        gemm(stream, zb, Wl, 256, conv_b + l * HDIM, nullptr, nullptr, Cacc, HDIM, 256, 256, N_pad, false, GY);
        spmm_pull_k<<<pg, pb, 0, stream>>>(zb, rowptr, col, wgt, p1, N);
        gemm(stream, p1, Wl + HH, 256, nullptr, Cacc, nullptr, Cacc, HDIM, 256, 256, N_pad, false, GY);
        spmm_pull_k<<<pg, pb, 0, stream>>>(p1, rowptr, col, wgt, p2, N);
        gemm(stream, p2, Wl + 2 * HH, 256, nullptr, Cacc, nullptr, zb, HDIM, 256, 256, N_pad, true, GY);

        // MLP over 4 hidden-col chunks; residual accumulated in Cacc (f32), h rounds once
        for (int blk = 0; blk < 4; ++blk) {
            const bf16* W1b = Wt_mlp1 + (size_t)l * 262144 + (size_t)blk * 256 * 256;
            const bf16* W2b = Wt_mlp2 + (size_t)l * 262144 + (size_t)blk * 256;
            gemm(stream, zb, W1b, 256, mlp_b1 + (size_t)l * 1024 + blk * HDIM,
                 nullptr, nullptr, p1, HDIM, 256, 256, N_pad, true, GY);
            hipMemsetAsync(stats, 0, 512 * 4, stream);
            colstats_k<<<dim3(256), dim3(256), 0, stream>>>(p1, stats, N);
            finalize_k<<<dim3(1), dim3(256), 0, stream>>>(stats, mlp_g + (size_t)l * 1024 + blk * HDIM,
                                                          mlp_bb + (size_t)l * 1024 + blk * HDIM, ab, invn);
            apply_bn_leaky_k<<<ag, abk, 0, stream>>>(p1, ab, p1, n4);
            if (blk == 0)
                gemm(stream, p1, W2b, 1024, mlp_b2 + l * HDIM, nullptr, hb, Cacc, HDIM, 256, 256, N_pad, false, GY);
            else if (blk < 3)
                gemm(stream, p1, W2b, 1024, nullptr, Cacc, nullptr, Cacc, HDIM, 256, 256, N_pad, false, GY);
            else
                gemm(stream, p1, W2b, 1024, nullptr, Cacc, nullptr, hb, HDIM, 256, 256, N_pad, true, GY);
        }
    }

    // out = hb @ W_out + b_out (f32, guarded store)
    gemm(stream, hb, Wt_out, 256, b_out, nullptr, nullptr, (float*)d_out, 128, 256, 128, N, false, GY);
}

// Round 5
// 2189.963 us; speedup vs baseline: 12.3578x; 1.8392x over previous
//
#include <hip/hip_runtime.h>

#define HDIM 256
#define EPSV 1e-5f
#define SLOPEV 0.01f

typedef __bf16 bf16;
typedef bf16  bf16x8 __attribute__((ext_vector_type(8)));
typedef bf16  bf16x4 __attribute__((ext_vector_type(4)));
typedef float f32x4  __attribute__((ext_vector_type(4)));

#define GLD16(g, l) __builtin_amdgcn_global_load_lds( \
    (const __attribute__((address_space(1))) void*)(g), \
    (__attribute__((address_space(3))) void*)(l), 16, 0, 0)

// ================= MFMA GEMM =================
// out[n x M] = concat_k(A0..A_{nseg-1})[n x nseg*segK] * Wt[M x K]^T + bias (+addb)
// A segments are separate buffers (row stride segK). Output segments of 256 cols
// go to out0..out3 (row stride ldo). Store bf16 or f32.
template<bool STORE_BF16>
__global__ __launch_bounds__(256)
void gemm_bt_k(const bf16* A0, const bf16* A1, const bf16* A2, const bf16* A3,
               int nseg, int segK,
               const bf16* __restrict__ Wt,
               const float* __restrict__ bias, const bf16* __restrict__ addb,
               void* out0, void* out1, void* out2, void* out3,
               int ldo, int n_store)
{
    __shared__ bf16 As[128 * 32];   // [m][k] 8 KB
    __shared__ bf16 Bs[128 * 32];   // [n][k] 8 KB
    const int tid  = threadIdx.x;
    const int wave = tid >> 6, lane = tid & 63;
    const int quad = lane >> 4, l16 = lane & 15;
    const int waveM = (wave >> 1) * 64, waveN = (wave & 1) * 64;
    const int bm = blockIdx.y * 128, bn = blockIdx.x * 128;
    const int K = nseg * segK;

    const bf16* segs[4] = {A0, A1, A2, A3};
    char* lA0 = (char*)As + wave * 1024;
    char* lA1 = (char*)As + 4096 + wave * 1024;
    char* lB0 = (char*)Bs + wave * 1024;
    char* lB1 = (char*)Bs + 4096 + wave * 1024;
    const bf16* pa = As + (waveM + l16) * 32 + quad * 8;
    const bf16* pb = Bs + (waveN + l16) * 32 + quad * 8;

    f32x4 acc[4][4] = {};

    for (int s = 0; s < nseg; ++s) {
        const bf16* A = segs[s];
        const char* gA0 = (const char*)(A + (size_t)(bm + (tid >> 2)) * segK + (tid & 3) * 8);
        const char* gA1 = (const char*)(A + (size_t)(bm + 64 + (tid >> 2)) * segK + (tid & 3) * 8);
        const char* gB0 = (const char*)(Wt + (size_t)(bn + (tid >> 2)) * K + s * segK + (tid & 3) * 8);
        const char* gB1 = (const char*)(Wt + (size_t)(bn + 64 + (tid >> 2)) * K + s * segK + (tid & 3) * 8);
        for (int kt = 0; kt < segK; kt += 32) {
            GLD16(gA0, lA0); GLD16(gA1, lA1);
            GLD16(gB0, lB0); GLD16(gB1, lB1);
            gA0 += 64; gA1 += 64; gB0 += 64; gB1 += 64;
            __syncthreads();

            bf16x8 a0 = *(const bf16x8*)(pa);
            bf16x8 a1 = *(const bf16x8*)(pa + 16 * 32);
            bf16x8 a2 = *(const bf16x8*)(pa + 32 * 32);
            bf16x8 a3 = *(const bf16x8*)(pa + 48 * 32);
            bf16x8 b0 = *(const bf16x8*)(pb);
            bf16x8 b1 = *(const bf16x8*)(pb + 16 * 32);
            bf16x8 b2 = *(const bf16x8*)(pb + 32 * 32);
            bf16x8 b3 = *(const bf16x8*)(pb + 48 * 32);

            acc[0][0] = __builtin_amdgcn_mfma_f32_16x16x32_bf16(a0, b0, acc[0][0], 0, 0, 0);
            acc[0][1] = __builtin_amdgcn_mfma_f32_16x16x32_bf16(a0, b1, acc[0][1], 0, 0, 0);
            acc[0][2] = __builtin_amdgcn_mfma_f32_16x16x32_bf16(a0, b2, acc[0][2], 0, 0, 0);
            acc[0][3] = __builtin_amdgcn_mfma_f32_16x16x32_bf16(a0, b3, acc[0][3], 0, 0, 0);
            acc[1][0] = __builtin_amdgcn_mfma_f32_16x16x32_bf16(a1, b0, acc[1][0], 0, 0, 0);
            acc[1][1] = __builtin_amdgcn_mfma_f32_16x16x32_bf16(a1, b1, acc[1][1], 0, 0, 0);
            acc[1][2] = __builtin_amdgcn_mfma_f32_16x16x32_bf16(a1, b2, acc[1][2], 0, 0, 0);
            acc[1][3] = __builtin_amdgcn_mfma_f32_16x16x32_bf16(a1, b3, acc[1][3], 0, 0, 0);
            acc[2][0] = __builtin_amdgcn_mfma_f32_16x16x32_bf16(a2, b0, acc[2][0], 0, 0, 0);
            acc[2][1] = __builtin_amdgcn_mfma_f32_16x16x32_bf16(a2, b1, acc[2][1], 0, 0, 0);
            acc[2][2] = __builtin_amdgcn_mfma_f32_16x16x32_bf16(a2, b2, acc[2][2], 0, 0, 0);
            acc[2][3] = __builtin_amdgcn_mfma_f32_16x16x32_bf16(a2, b3, acc[2][3], 0, 0, 0);
            acc[3][0] = __builtin_amdgcn_mfma_f32_16x16x32_bf16(a3, b0, acc[3][0], 0, 0, 0);
            acc[3][1] = __builtin_amdgcn_mfma_f32_16x16x32_bf16(a3, b1, acc[3][1], 0, 0, 0);
            acc[3][2] = __builtin_amdgcn_mfma_f32_16x16x32_bf16(a3, b2, acc[3][2], 0, 0, 0);
            acc[3][3] = __builtin_amdgcn_mfma_f32_16x16x32_bf16(a3, b3, acc[3][3], 0, 0, 0);
            __syncthreads();
        }
    }

    float bv[4];
#pragma unroll
    for (int j = 0; j < 4; ++j)
        bv[j] = bias ? bias[bn + waveN + j * 16 + l16] : 0.f;

    void* outs[4] = {out0, out1, out2, out3};
#pragma unroll
    for (int i = 0; i < 4; ++i) {
#pragma unroll
        for (int j = 0; j < 4; ++j) {
            int colg = bn + waveN + j * 16 + l16;
            int cseg = colg >> 8, cloc = colg & 255;
#pragma unroll
            for (int r = 0; r < 4; ++r) {
                int rowg = bm + waveM + i * 16 + quad * 4 + r;
                if (rowg < n_store) {
                    size_t idx = (size_t)rowg * ldo + cloc;
                    float v = acc[i][j][r] + bv[j];
                    if (addb) v += (float)addb[idx];
                    if (STORE_BF16) ((bf16*)outs[cseg])[idx] = (bf16)v;
                    else            ((float*)outs[cseg])[idx] = v;
                }
            }
        }
    }
}

// ================= transpose+convert =================
// dst[grp][m][sub*Kseg + k] = (bf16)src[z][k][m];  z = grp*G + sub, ldd = G*Kseg
__global__ __launch_bounds__(256)
void transpose_cvt_k(const float* __restrict__ src, bf16* __restrict__ dst,
                     int Kseg, int M, int G)
{
    __shared__ float t[32][33];
    const int z = blockIdx.z;
    src += (size_t)z * Kseg * M;
    const int ldd = G * Kseg;
    dst += (size_t)(z / G) * M * ldd + (size_t)(z % G) * Kseg;
    const int tM = blockIdx.x * 32, tK = blockIdx.y * 32;
    const int tx = threadIdx.x & 31, ty = threadIdx.x >> 5;
#pragma unroll
    for (int r = 0; r < 4; ++r)
        t[ty + r * 8][tx] = src[(size_t)(tK + ty + r * 8) * M + tM + tx];
    __syncthreads();
#pragma unroll
    for (int r = 0; r < 4; ++r)
        dst[(size_t)(tM + ty + r * 8) * ldd + tK + tx] = (bf16)t[tx][ty + r * 8];
}

__global__ __launch_bounds__(256)
void cvt_bf_k(const float* __restrict__ src, bf16* __restrict__ dst, long n4)
{
    long i = (long)blockIdx.x * blockDim.x + threadIdx.x;
    if (i >= n4) return;
    float4 v = ((const float4*)src)[i];
    bf16x4 o; o[0] = (bf16)v.x; o[1] = (bf16)v.y; o[2] = (bf16)v.z; o[3] = (bf16)v.w;
    ((bf16x4*)dst)[i] = o;
}

// ================= CSR build =================
__global__ __launch_bounds__(256)
void deg_k(const int* __restrict__ dst, int* __restrict__ deg, int E)
{
    int e = blockIdx.x * blockDim.x + threadIdx.x;
    if (e < E) atomicAdd(&deg[dst[e]], 1);
}

// single block: rowptr = exclusive scan (len N+1); wp = exclusive scan (len N)
__global__ __launch_bounds__(1024)
void scan_k(int* __restrict__ deg_wp, int* __restrict__ rowptr, int N)
{
    __shared__ int s[1024];
    const int tid = threadIdx.x;
    if (tid == 0) rowptr[0] = 0;
    int running = 0;
    for (int base = 0; base < N; base += 1024) {
        int i = base + tid;
        int x = (i < N) ? deg_wp[i] : 0;
        s[tid] = x;
        __syncthreads();
        for (int off = 1; off < 1024; off <<= 1) {
            int t = (tid >= off) ? s[tid - off] : 0;
            __syncthreads();
            s[tid] += t;
            __syncthreads();
        }
        if (i < N) {
            rowptr[i + 1] = s[tid] + running;
            deg_wp[i]     = s[tid] + running - x;   // exclusive -> reorder write ptr
        }
        running += s[1023];
        __syncthreads();
    }
}

__global__ __launch_bounds__(256)
void reorder_k(const int* __restrict__ src, const int* __restrict__ dst,
               const float* __restrict__ ew, int* __restrict__ wp,
               int* __restrict__ col, float* __restrict__ wgt, int E)
{
    int e = blockIdx.x * blockDim.x + threadIdx.x;
    if (e >= E) return;
    int d = dst[e];
    int pos = atomicAdd(&wp[d], 1);
    col[pos] = src[e];
    wgt[pos] = ew[e];
}

// ================= pull SpMM (bf16 features, fp32 accum) =================
__global__ __launch_bounds__(256)
void spmm_pull_k(const bf16* __restrict__ P, const int* __restrict__ rowptr,
                 const int* __restrict__ col, const float* __restrict__ wgt,
                 bf16* __restrict__ Q, int N)
{
    int node = blockIdx.x * 4 + (threadIdx.x >> 6);
    int lane = threadIdx.x & 63;
    if (node >= N) return;
    int e = rowptr[node], end = rowptr[node + 1];
    float ax = 0.f, ay = 0.f, az = 0.f, aw = 0.f;
    for (; e < end; ++e) {
        int s = col[e];
        float w = wgt[e];
        bf16x4 v = *(const bf16x4*)(P + (size_t)s * HDIM + lane * 4);
        ax += (float)v[0] * w; ay += (float)v[1] * w;
        az += (float)v[2] * w; aw += (float)v[3] * w;
    }
    bf16x4 o; o[0] = (bf16)ax; o[1] = (bf16)ay; o[2] = (bf16)az; o[3] = (bf16)aw;
    *(bf16x4*)(Q + (size_t)node * HDIM + lane * 4) = o;
}

// ================= BN: stats (atomic into pre-zeroed slot) =================
__global__ __launch_bounds__(256)
void colstats_k(const bf16* __restrict__ X, float* __restrict__ s, int n)
{
    int c = threadIdx.x;
    float a = 0.f, b = 0.f;
    for (int r = blockIdx.x; r < n; r += gridDim.x) {
        float v = (float)X[(size_t)r * HDIM + c];
        a += v; b += v * v;
    }
    unsafeAtomicAdd(&s[c], a);
    unsafeAtomicAdd(&s[HDIM + c], b);
}

__global__ __launch_bounds__(256)
void colstats4_k(const bf16* X0, const bf16* X1, const bf16* X2, const bf16* X3,
                 float* __restrict__ s, int n)
{
    const bf16* Xs[4] = {X0, X1, X2, X3};
    int c = threadIdx.x;
    float a[4] = {}, b[4] = {};
    for (int r = blockIdx.x; r < n; r += gridDim.x) {
#pragma unroll
        for (int q = 0; q < 4; ++q) {
            float v = (float)Xs[q][(size_t)r * HDIM + c];
            a[q] += v; b[q] += v * v;
        }
    }
#pragma unroll
    for (int q = 0; q < 4; ++q) {
        unsafeAtomicAdd(&s[q * 256 + c], a[q]);
        unsafeAtomicAdd(&s[1024 + q * 256 + c], b[q]);
    }
}

// ================= BN apply (fused finalize) =================
__global__ __launch_bounds__(256)
void apply_bn_k(const bf16* __restrict__ X, const float* __restrict__ s,
                const float* __restrict__ g, const float* __restrict__ bb,
                bf16* __restrict__ Y, int n, float invn)
{
    __shared__ float aL[256], bL[256];
    const int tid = threadIdx.x;
    {
        float mean = s[tid] * invn;
        float var  = s[256 + tid] * invn - mean * mean;
        float a = g[tid] * rsqrtf(var + EPSV);
        aL[tid] = a; bL[tid] = bb[tid] - mean * a;
    }
    __syncthreads();
    long n4 = (long)n * 64;
    for (long i = (long)blockIdx.x * 256 + tid; i < n4; i += (long)gridDim.x * 256) {
        bf16x4 v = ((const bf16x4*)X)[i];
        int c4 = (int)(i & 63) * 4;
        float r0 = fmaf((float)v[0], aL[c4 + 0], bL[c4 + 0]); r0 = r0 > 0.f ? r0 : SLOPEV * r0;
        float r1 = fmaf((float)v[1], aL[c4 + 1], bL[c4 + 1]); r1 = r1 > 0.f ? r1 : SLOPEV * r1;
        float r2 = fmaf((float)v[2], aL[c4 + 2], bL[c4 + 2]); r2 = r2 > 0.f ? r2 : SLOPEV * r2;
        float r3 = fmaf((float)v[3], aL[c4 + 3], bL[c4 + 3]); r3 = r3 > 0.f ? r3 : SLOPEV * r3;
        bf16x4 o; o[0] = (bf16)r0; o[1] = (bf16)r1; o[2] = (bf16)r2; o[3] = (bf16)r3;
        ((bf16x4*)Y)[i] = o;
    }
}

__global__ __launch_bounds__(256)
void apply_bn4_k(bf16* X0, bf16* X1, bf16* X2, bf16* X3,
                 const float* __restrict__ s, const float* __restrict__ g,
                 const float* __restrict__ bb, int n, float invn)
{
    __shared__ float aL[1024], bL[1024];
    const int tid = threadIdx.x;
#pragma unroll
    for (int q = 0; q < 4; ++q) {
        int c = q * 256 + tid;
        float mean = s[c] * invn;
        float var  = s[1024 + c] * invn - mean * mean;
        float a = g[c] * rsqrtf(var + EPSV);
        aL[c] = a; bL[c] = bb[c] - mean * a;
    }
    __syncthreads();
    bf16* Xs[4] = {X0, X1, X2, X3};
    long per = (long)n * 64;
    long stride = (long)gridDim.x * 256;
    for (int q = 0; q < 4; ++q) {
        bf16* X = Xs[q];
        int cbase = q * 256;
        for (long i = (long)blockIdx.x * 256 + tid; i < per; i += stride) {
            bf16x4 v = ((const bf16x4*)X)[i];
            int c4 = cbase + (int)(i & 63) * 4;
            float r0 = fmaf((float)v[0], aL[c4 + 0], bL[c4 + 0]); r0 = r0 > 0.f ? r0 : SLOPEV * r0;
            float r1 = fmaf((float)v[1], aL[c4 + 1], bL[c4 + 1]); r1 = r1 > 0.f ? r1 : SLOPEV * r1;
            float r2 = fmaf((float)v[2], aL[c4 + 2], bL[c4 + 2]); r2 = r2 > 0.f ? r2 : SLOPEV * r2;
            float r3 = fmaf((float)v[3], aL[c4 + 3], bL[c4 + 3]); r3 = r3 > 0.f ? r3 : SLOPEV * r3;
            bf16x4 o; o[0] = (bf16)r0; o[1] = (bf16)r1; o[2] = (bf16)r2; o[3] = (bf16)r3;
            ((bf16x4*)X)[i] = o;
        }
    }
}

// ================= host =================
static void gemm(hipStream_t st, const bf16* A0, const bf16* A1, const bf16* A2, const bf16* A3,
                 int nseg, int segK, const bf16* Wt, const float* bias, const bf16* addb,
                 void* o0, void* o1, void* o2, void* o3, int ldo, int M, int n_store,
                 bool store_bf16, int GY)
{
    dim3 g(M / 128, GY), b(256);
    if (store_bf16)
        gemm_bt_k<true><<<g, b, 0, st>>>(A0, A1, A2, A3, nseg, segK, Wt, bias, addb,
                                         o0, o1, o2, o3, ldo, n_store);
    else
        gemm_bt_k<false><<<g, b, 0, st>>>(A0, A1, A2, A3, nseg, segK, Wt, bias, addb,
                                          o0, o1, o2, o3, ldo, n_store);
}

extern "C" void kernel_launch(void* const* d_in, const int* in_sizes, int n_in,
                              void* d_out, int out_size, void* d_ws, size_t ws_size,
                              hipStream_t stream)
{
    const float* x       = (const float*)d_in[0];
    const int*   ei      = (const int*)d_in[1];
    const float* ew      = (const float*)d_in[2];
    const float* W_emb   = (const float*)d_in[3];
    const float* b_emb   = (const float*)d_in[4];
    const float* conv0_W = (const float*)d_in[5];
    const float* conv0_b = (const float*)d_in[6];
    const float* norm_g  = (const float*)d_in[7];
    const float* norm_b  = (const float*)d_in[8];
    const float* conv_W  = (const float*)d_in[9];
    const float* conv_b  = (const float*)d_in[10];
    const float* mlp_W1  = (const float*)d_in[11];
    const float* mlp_b1  = (const float*)d_in[12];
    const float* mlp_g   = (const float*)d_in[13];
    const float* mlp_bb  = (const float*)d_in[14];
    const float* mlp_W2  = (const float*)d_in[15];
    const float* mlp_b2  = (const float*)d_in[16];
    const float* W_out   = (const float*)d_in[17];
    const float* b_out   = (const float*)d_in[18];

    const int N = in_sizes[0] / 128;          // 50000
    const int E = in_sizes[2];                // 800000
    const int* srcI = ei;
    const int* dstI = ei + E;
    const int N_pad = ((N + 127) / 128) * 128;   // 50048
    const int GY = N_pad / 128;

    const size_t NHp = (size_t)N_pad * HDIM;     // elements per activation buffer
    bf16* xb = (bf16*)d_ws;                      // N_pad x 128
    bf16* hb = xb + (size_t)N_pad * 128;
    bf16* zb = hb + NHp;
    bf16* cb = zb + NHp;
    bf16* p1 = cb + NHp;
    bf16* p2 = p1 + NHp;
    bf16* c1 = p2 + NHp;
    bf16* wa = c1 + NHp;                         // weight arena (2424832 bf16)
    bf16* Wt_emb   = wa;
    bf16* Wt_conv0 = wa + 32768;                 // 256 x 768
    bf16* Wt_conv  = wa + 229376;                // 3 x (256 x 768)
    bf16* Wt_mlp1  = wa + 819200;                // 3 x (1024 x 256)
    bf16* Wt_mlp2  = wa + 1605632;               // 3 x (256 x 1024)
    bf16* Wt_out   = wa + 2392064;               // 128 x 256
    float* stats  = (float*)(wa + 2424832);      // 3*512 + 3*2048 = 7680 floats
    int*   rowptr = (int*)(stats + 7680);        // N+1
    int*   wp     = rowptr + (N + 1);            // N
    int*   col    = wp + N;                      // E
    float* wgt    = (float*)(col + E);           // E

    const float invn = 1.0f / (float)N;
    dim3 pg((N + 3) / 4), pb(256);

    // ---- CSR build ----
    hipMemsetAsync(wp, 0, (size_t)N * 4, stream);
    deg_k<<<dim3((E + 255) / 256), dim3(256), 0, stream>>>(dstI, wp, E);
    scan_k<<<dim3(1), dim3(1024), 0, stream>>>(wp, rowptr, N);
    reorder_k<<<dim3((E + 255) / 256), dim3(256), 0, stream>>>(srcI, dstI, ew, wp, col, wgt, E);

    // ---- stats slots zero (finalize is fused; slots used once each) ----
    hipMemsetAsync(stats, 0, 7680 * 4, stream);

    // ---- convert inputs/weights ----
    cvt_bf_k<<<dim3((N * 32 + 255) / 256), dim3(256), 0, stream>>>(x, xb, (long)N * 32);
    transpose_cvt_k<<<dim3(8, 4, 1), dim3(256), 0, stream>>>(W_emb, Wt_emb, 128, 256, 1);
    transpose_cvt_k<<<dim3(8, 8, 3), dim3(256), 0, stream>>>(conv0_W, Wt_conv0, 256, 256, 3);
    transpose_cvt_k<<<dim3(8, 8, 9), dim3(256), 0, stream>>>(conv_W, Wt_conv, 256, 256, 3);
    transpose_cvt_k<<<dim3(32, 8, 3), dim3(256), 0, stream>>>(mlp_W1, Wt_mlp1, 256, 1024, 1);
    transpose_cvt_k<<<dim3(8, 32, 3), dim3(256), 0, stream>>>(mlp_W2, Wt_mlp2, 1024, 256, 1);
    transpose_cvt_k<<<dim3(4, 8, 1), dim3(256), 0, stream>>>(W_out, Wt_out, 256, 128, 1);

    // ---- embed: zb = bf16(x @ W_emb + b_emb) ----
    gemm(stream, xb, xb, xb, xb, 1, 128, Wt_emb, b_emb, nullptr,
         zb, zb, zb, zb, HDIM, 256, N_pad, true, GY);

    // ---- conv0: hb = [zb|A.zb|A^2.zb] @ [W0;W1;W2] + b  (single K=768 GEMM) ----
    spmm_pull_k<<<pg, pb, 0, stream>>>(zb, rowptr, col, wgt, p1, N);
    spmm_pull_k<<<pg, pb, 0, stream>>>(p1, rowptr, col, wgt, p2, N);
    gemm(stream, zb, p1, p2, p2, 3, 256, Wt_conv0, conv0_b, nullptr,
         hb, hb, hb, hb, HDIM, 256, N_pad, true, GY);

    for (int l = 0; l < 3; ++l) {
        float* sh = stats + l * 512;
        float* sm = stats + 1536 + l * 2048;

        // zb = leaky(bn(hb))
        colstats_k<<<dim3(1024), dim3(256), 0, stream>>>(hb, sh, N);
        apply_bn_k<<<dim3(1024), dim3(256), 0, stream>>>(hb, sh, norm_g + l * 256,
                                                         norm_b + l * 256, zb, N, invn);

        // conv: cb = [zb|A.zb|A^2.zb] @ Wl + b
        spmm_pull_k<<<pg, pb, 0, stream>>>(zb, rowptr, col, wgt, p1, N);
        spmm_pull_k<<<pg, pb, 0, stream>>>(p1, rowptr, col, wgt, p2, N);
        gemm(stream, zb, p1, p2, p2, 3, 256, Wt_conv + (size_t)l * 196608,
             conv_b + l * 256, nullptr, cb, cb, cb, cb, HDIM, 256, N_pad, true, GY);

        // MLP hidden: {zb,p1,p2,c1} = cb @ W1 + b1  (M=1024, 4 out segments)
        gemm(stream, cb, cb, cb, cb, 1, 256, Wt_mlp1 + (size_t)l * 262144,
             mlp_b1 + (size_t)l * 1024, nullptr, zb, p1, p2, c1, HDIM, 1024, N_pad, true, GY);
        colstats4_k<<<dim3(1024), dim3(256), 0, stream>>>(zb, p1, p2, c1, sm, N);
        apply_bn4_k<<<dim3(2048), dim3(256), 0, stream>>>(zb, p1, p2, c1, sm,
                                                          mlp_g + (size_t)l * 1024,
                                                          mlp_bb + (size_t)l * 1024, N, invn);

        // hb += hidden @ W2 + b2  (single K=1024 GEMM, residual in epilogue)
        gemm(stream, zb, p1, p2, c1, 4, 256, Wt_mlp2 + (size_t)l * 262144,
             mlp_b2 + l * 256, hb, hb, hb, hb, hb, HDIM, 256, N_pad, true, GY);
    }

    // ---- out = hb @ W_out + b_out (f32, guarded) ----
    gemm(stream, hb, hb, hb, hb, 1, 256, Wt_out, b_out, nullptr,
         d_out, d_out, d_out, d_out, 128, 128, N, false, GY);
}